// Round 1
// baseline (792.086 us; speedup 1.0000x reference)
//
#include <hip/hip_runtime.h>
#include <stdint.h>

#define Bz 4
#define Sz 4096
#define Dz 2048
#define Hz 16
#define HDz 128
#define NTz 8
#define TILEz 16

typedef __bf16 bf16x8 __attribute__((ext_vector_type(8)));
typedef float f32x4 __attribute__((ext_vector_type(4)));
typedef float fx4 __attribute__((ext_vector_type(4)));
typedef unsigned short u16;
typedef u16 u16x4 __attribute__((ext_vector_type(4)));
typedef u16 u16x8 __attribute__((ext_vector_type(8)));

#define MFMA16(a, b, c) __builtin_amdgcn_mfma_f32_16x16x32_bf16((a), (b), (c), 0, 0, 0)

__device__ __forceinline__ u16 f2bf(float f) {
    uint32_t u = __builtin_bit_cast(uint32_t, f);
    return (u16)((u + 0x7fffu + ((u >> 16) & 1u)) >> 16);  // RNE
}

// async global->LDS, 16B per lane. LDS dest must be wave-uniform base; HW adds lane*16.
__device__ __forceinline__ void async16(const u16* g, u16* l) {
    __builtin_amdgcn_global_load_lds(
        (const __attribute__((address_space(1))) unsigned int*)(g),
        (__attribute__((address_space(3))) unsigned int*)(l), 16, 0, 0);
}

// ---------------- convert x (fp32 -> bf16), 8 elems/thread ----------------
__global__ void cvt_x(const float* __restrict__ x, u16* __restrict__ o) {
    int i = blockIdx.x * 256 + threadIdx.x;
    const fx4* xv = (const fx4*)x;
    fx4 a = xv[i * 2], b = xv[i * 2 + 1];
    u16x8 r;
    r[0] = f2bf(a[0]); r[1] = f2bf(a[1]); r[2] = f2bf(a[2]); r[3] = f2bf(a[3]);
    r[4] = f2bf(b[0]); r[5] = f2bf(b[1]); r[6] = f2bf(b[2]); r[7] = f2bf(b[3]);
    ((u16x8*)o)[i] = r;
}

// ---------------- transpose + convert weights: (2048 x 2048) fp32 -> bf16 N x K ----------------
__global__ void transpose_cvt(const float* W0, const float* W1, const float* W2, const float* W3,
                              u16* O0, u16* O1, u16* O2, u16* O3) {
    const float* W; u16* O;
    switch (blockIdx.z) {
        case 0: W = W0; O = O0; break;
        case 1: W = W1; O = O1; break;
        case 2: W = W2; O = O2; break;
        default: W = W3; O = O3; break;
    }
    __shared__ u16 tile[32][33];
    int bx = blockIdx.x * 32, by = blockIdx.y * 32;
    int tx = threadIdx.x, ty = threadIdx.y;
#pragma unroll
    for (int i = 0; i < 32; i += 8)
        tile[ty + i][tx] = f2bf(W[(long)(by + ty + i) * 2048 + bx + tx]);
    __syncthreads();
#pragma unroll
    for (int i = 0; i < 32; i += 8)
        O[(long)(bx + ty + i) * 2048 + by + tx] = tile[tx][ty + i];
}

// ---------------- m97-style GEMM: C(MxN) = A(MxK) * BT(NxK)^T, bf16 in ----------------
template <typename OutT>
__global__ __launch_bounds__(256) void gemm_bt(const u16* __restrict__ A, const u16* __restrict__ BT,
                                               OutT* __restrict__ C, int M_, int N_, int K_) {
    __shared__ __align__(16) u16 As[4096];  // 128 x 32
    __shared__ __align__(16) u16 Bs[4096];  // 128 x 32
    const int t = threadIdx.x, w = t >> 6, l = t & 63, lr = l & 15, quad = l >> 4;
    const int bm = blockIdx.x, bn = blockIdx.y;
    const u16* gA[2]; const u16* gB[2]; u16* lA[2]; u16* lB[2];
#pragma unroll
    for (int r = 0; r < 2; r++) {
        int c = r * 256 + t;
        gA[r] = A + (long)(bm * 128 + (c >> 2)) * K_ + (c & 3) * 8;
        gB[r] = BT + (long)(bn * 128 + (c >> 2)) * K_ + (c & 3) * 8;
        lA[r] = &As[(r * 256 + w * 64) * 8];
        lB[r] = &Bs[(r * 256 + w * 64) * 8];
    }
    f32x4 acc[4][4] = {};
    const int wr = (w >> 1) * 64, wc = (w & 1) * 64;
    for (int k0 = 0; k0 < K_; k0 += 32) {
        async16(gA[0] + k0, lA[0]); async16(gA[1] + k0, lA[1]);
        async16(gB[0] + k0, lB[0]); async16(gB[1] + k0, lB[1]);
        __syncthreads();
        bf16x8 af[4], bfr[4];
#pragma unroll
        for (int i = 0; i < 4; i++) af[i] = *(const bf16x8*)&As[(wr + i * 16 + lr) * 32 + quad * 8];
#pragma unroll
        for (int j = 0; j < 4; j++) bfr[j] = *(const bf16x8*)&Bs[(wc + j * 16 + lr) * 32 + quad * 8];
#pragma unroll
        for (int i = 0; i < 4; i++)
#pragma unroll
            for (int j = 0; j < 4; j++) acc[i][j] = MFMA16(af[i], bfr[j], acc[i][j]);
        __syncthreads();
    }
#pragma unroll
    for (int i = 0; i < 4; i++) {
        int row0 = bm * 128 + wr + i * 16 + quad * 4;
#pragma unroll
        for (int j = 0; j < 4; j++) {
            int col = bn * 128 + wc + j * 16 + lr;
#pragma unroll
            for (int rg = 0; rg < 4; rg++) {
                long idx = (long)(row0 + rg) * N_ + col;
                if constexpr (sizeof(OutT) == 2) ((u16*)C)[idx] = f2bf(acc[i][j][rg]);
                else ((float*)C)[idx] = acc[i][j][rg];
            }
        }
    }
}

// ---------------- sparse K/V projection (gathered rows), per (b,h,{K|V}) ----------------
// which==0: ksp[bh][kk][d]  = x[b,tok_kk,:] . WkT[h*128+d,:]
// which==1: vspT[bh][d][kk] = WvT[h*128+d,:] . x[b,tok_kk,:]   (operand roles swapped -> transposed out)
__global__ __launch_bounds__(256) void kv_sparse(const u16* __restrict__ xbf, const u16* __restrict__ WkT,
                                                 const u16* __restrict__ WvT, const int* __restrict__ anchor,
                                                 u16* __restrict__ ksp, u16* __restrict__ vspT) {
    const int bh = blockIdx.x, which = blockIdx.y;
    const int b = bh >> 4, h = bh & 15;
    __shared__ int toks[128];
    __shared__ __align__(16) u16 As[4096];
    __shared__ __align__(16) u16 Bs[4096];
    const int t = threadIdx.x, w = t >> 6, l = t & 63, lr = l & 15, quad = l >> 4;
    if (t < 128) {
        int j = t >> 4;
        int tile = (j == 7) ? (Sz / TILEz - 1) : anchor[bh * NTz + j];
        toks[t] = tile * TILEz + (t & 15);
    }
    __syncthreads();
    const u16* gA[2]; const u16* gB[2]; u16* lA[2]; u16* lB[2];
#pragma unroll
    for (int r = 0; r < 2; r++) {
        int c = r * 256 + t;
        int row = c >> 2, col8 = (c & 3) * 8;
        const u16* xrow = xbf + ((long)b * Sz + toks[row]) * Dz + col8;
        const u16* wrowK = WkT + (long)(h * HDz + row) * Dz + col8;
        const u16* wrowV = WvT + (long)(h * HDz + row) * Dz + col8;
        gA[r] = (which == 0) ? xrow : wrowV;
        gB[r] = (which == 0) ? wrowK : xrow;
        lA[r] = &As[(r * 256 + w * 64) * 8];
        lB[r] = &Bs[(r * 256 + w * 64) * 8];
    }
    f32x4 acc[4][4] = {};
    const int wr = (w >> 1) * 64, wc = (w & 1) * 64;
    for (int k0 = 0; k0 < Dz; k0 += 32) {
        async16(gA[0] + k0, lA[0]); async16(gA[1] + k0, lA[1]);
        async16(gB[0] + k0, lB[0]); async16(gB[1] + k0, lB[1]);
        __syncthreads();
        bf16x8 af[4], bfr[4];
#pragma unroll
        for (int i = 0; i < 4; i++) af[i] = *(const bf16x8*)&As[(wr + i * 16 + lr) * 32 + quad * 8];
#pragma unroll
        for (int j = 0; j < 4; j++) bfr[j] = *(const bf16x8*)&Bs[(wc + j * 16 + lr) * 32 + quad * 8];
#pragma unroll
        for (int i = 0; i < 4; i++)
#pragma unroll
            for (int j = 0; j < 4; j++) acc[i][j] = MFMA16(af[i], bfr[j], acc[i][j]);
        __syncthreads();
    }
    u16* out = ((which == 0) ? ksp : vspT) + (long)bh * HDz * 128;
#pragma unroll
    for (int i = 0; i < 4; i++) {
        int row0 = wr + i * 16 + quad * 4;
#pragma unroll
        for (int j = 0; j < 4; j++) {
            int col = wc + j * 16 + lr;
#pragma unroll
            for (int rg = 0; rg < 4; rg++) out[(row0 + rg) * 128 + col] = f2bf(acc[i][j][rg]);
        }
    }
}

// ---------------- attention: per (128-query tile, h, b) ----------------
__global__ __launch_bounds__(256) void attn_kernel(u16* QAO,  // Q in (B*S,2048), out written in place (disjoint tiles)
                                                   const u16* __restrict__ ksp, const u16* __restrict__ vspT,
                                                   const int* __restrict__ anchor) {
    const int st = blockIdx.x, h = blockIdx.y, b = blockIdx.z;
    const int bh = b * Hz + h, s0 = st * 128;
    __shared__ __align__(16) u16 Ps[128 * 136];  // pad 128->136 to dodge bank conflicts
    __shared__ int toks[128];
    const int t = threadIdx.x, w = t >> 6, l = t & 63, lr = l & 15, quad = l >> 4;
    if (t < 128) {
        int j = t >> 4;
        int tile = (j == 7) ? (Sz / TILEz - 1) : anchor[bh * NTz + j];
        toks[t] = tile * TILEz + (t & 15);
    }
    __syncthreads();
    const u16* Qb = QAO + (long)(b * Sz + s0 + w * 32) * 2048 + h * HDz;
    const u16* Kb = ksp + (long)bh * HDz * 128;   // [key][d]
    const u16* Vb = vspT + (long)bh * HDz * 128;  // [d][key]
    // --- S = Q K^T : wave w owns query rows w*32..w*32+31, all 128 keys ---
    f32x4 acc[2][8] = {};
#pragma unroll
    for (int ks = 0; ks < 4; ks++) {
        bf16x8 a0 = *(const bf16x8*)(Qb + (long)lr * 2048 + ks * 32 + quad * 8);
        bf16x8 a1 = *(const bf16x8*)(Qb + (long)(16 + lr) * 2048 + ks * 32 + quad * 8);
#pragma unroll
        for (int j = 0; j < 8; j++) {
            bf16x8 bj = *(const bf16x8*)(Kb + (j * 16 + lr) * 128 + ks * 32 + quad * 8);
            acc[0][j] = MFMA16(a0, bj, acc[0][j]);
            acc[1][j] = MFMA16(a1, bj, acc[1][j]);
        }
    }
    // --- mask + softmax, fully in-register (rows live in 16-lane quad groups) ---
    int tokj[8];
#pragma unroll
    for (int j = 0; j < 8; j++) tokj[j] = toks[j * 16 + lr];
    const float scale = 0.08838834764831845f;  // 1/sqrt(128)
#pragma unroll
    for (int i = 0; i < 2; i++) {
#pragma unroll
        for (int rg = 0; rg < 4; rg++) {
            int qpos = s0 + w * 32 + i * 16 + quad * 4 + rg;
            float v[8];
#pragma unroll
            for (int j = 0; j < 8; j++)
                v[j] = (tokj[j] > qpos) ? -1e10f : acc[i][j][rg] * scale;
            float mx = v[0];
#pragma unroll
            for (int j = 1; j < 8; j++) mx = fmaxf(mx, v[j]);
            mx = fmaxf(mx, __shfl_xor(mx, 1, 64));
            mx = fmaxf(mx, __shfl_xor(mx, 2, 64));
            mx = fmaxf(mx, __shfl_xor(mx, 4, 64));
            mx = fmaxf(mx, __shfl_xor(mx, 8, 64));
            float s = 0.f;
#pragma unroll
            for (int j = 0; j < 8; j++) { v[j] = exp2f((v[j] - mx) * 1.4426950408889634f); s += v[j]; }
            s += __shfl_xor(s, 1, 64);
            s += __shfl_xor(s, 2, 64);
            s += __shfl_xor(s, 4, 64);
            s += __shfl_xor(s, 8, 64);
            float rs = 1.0f / s;
            int prow = w * 32 + i * 16 + quad * 4 + rg;
#pragma unroll
            for (int j = 0; j < 8; j++) Ps[prow * 136 + j * 16 + lr] = f2bf(v[j] * rs);
        }
    }
    __syncthreads();
    // --- O^T = V^T P^T : wave w owns d-rows w*32..w*32+31, all 128 queries ---
    f32x4 oacc[2][8] = {};
#pragma unroll
    for (int ks = 0; ks < 4; ks++) {
        bf16x8 a0 = *(const bf16x8*)(Vb + (w * 32 + lr) * 128 + ks * 32 + quad * 8);
        bf16x8 a1 = *(const bf16x8*)(Vb + (w * 32 + 16 + lr) * 128 + ks * 32 + quad * 8);
#pragma unroll
        for (int j = 0; j < 8; j++) {
            bf16x8 bj = *(const bf16x8*)&Ps[(j * 16 + lr) * 136 + ks * 32 + quad * 8];
            oacc[0][j] = MFMA16(a0, bj, oacc[0][j]);
            oacc[1][j] = MFMA16(a1, bj, oacc[1][j]);
        }
    }
#pragma unroll
    for (int i = 0; i < 2; i++) {
#pragma unroll
        for (int j = 0; j < 8; j++) {
            u16x4 pk;
#pragma unroll
            for (int rg = 0; rg < 4; rg++) pk[rg] = f2bf(oacc[i][j][rg]);
            int d = w * 32 + i * 16 + quad * 4;
            int q = j * 16 + lr;
            *(u16x4*)(QAO + (long)(b * Sz + s0 + q) * 2048 + h * HDz + d) = pk;
        }
    }
}

extern "C" void kernel_launch(void* const* d_in, const int* in_sizes, int n_in,
                              void* d_out, int out_size, void* d_ws, size_t ws_size,
                              hipStream_t stream) {
    const float* x = (const float*)d_in[0];
    const int* anchor = (const int*)d_in[1];
    const float* Wq = (const float*)d_in[2];
    const float* Wk = (const float*)d_in[3];
    const float* Wv = (const float*)d_in[4];
    const float* Wo = (const float*)d_in[5];

    char* ws = (char*)d_ws;
    const size_t XB = 67108864;   // x bf16: 16384*2048*2
    const size_t WB = 8388608;    // one weight bf16: 2048*2048*2
    u16* xbf = (u16*)(ws);
    u16* WqT = (u16*)(ws + XB);
    u16* WkT = (u16*)(ws + XB + WB);
    u16* WvT = (u16*)(ws + XB + 2 * WB);
    u16* WoT = (u16*)(ws + XB + 3 * WB);
    u16* Qb  = (u16*)(ws + XB + 4 * WB);            // Q, then attn out (aliased, disjoint tiles)
    u16* ksp = (u16*)(ws + 2 * XB + 4 * WB);        // (B*H,128,128)
    u16* vspT= (u16*)(ws + 2 * XB + 4 * WB + 2097152);

    cvt_x<<<16384, 256, 0, stream>>>(x, xbf);
    transpose_cvt<<<dim3(64, 64, 4), dim3(32, 8), 0, stream>>>(Wq, Wk, Wv, Wo, WqT, WkT, WvT, WoT);
    gemm_bt<u16><<<dim3(128, 16), 256, 0, stream>>>(xbf, WqT, Qb, 16384, 2048, 2048);
    kv_sparse<<<dim3(64, 2), 256, 0, stream>>>(xbf, WkT, WvT, anchor, ksp, vspT);
    attn_kernel<<<dim3(32, 16, 4), 256, 0, stream>>>(Qb, ksp, vspT, anchor);
    gemm_bt<float><<<dim3(128, 16), 256, 0, stream>>>(Qb, WoT, (float*)d_out, 16384, 2048, 2048);
}

// Round 3
// 752.798 us; speedup vs baseline: 1.0522x; 1.0522x over previous
//
#include <hip/hip_runtime.h>
#include <stdint.h>

#define Bz 4
#define Sz 4096
#define Dz 2048
#define Hz 16
#define HDz 128
#define NTz 8
#define TILEz 16

typedef __bf16 bf16x8 __attribute__((ext_vector_type(8)));
typedef float f32x4 __attribute__((ext_vector_type(4)));
typedef float fx4 __attribute__((ext_vector_type(4)));
typedef unsigned short u16;
typedef u16 u16x4 __attribute__((ext_vector_type(4)));
typedef u16 u16x8 __attribute__((ext_vector_type(8)));

#define MFMA16(a, b, c) __builtin_amdgcn_mfma_f32_16x16x32_bf16((a), (b), (c), 0, 0, 0)

__device__ __forceinline__ u16 f2bf(float f) {
    uint32_t u = __builtin_bit_cast(uint32_t, f);
    return (u16)((u + 0x7fffu + ((u >> 16) & 1u)) >> 16);  // RNE
}

// async global->LDS, 16B per lane. LDS dest must be wave-uniform base; HW adds lane*16.
__device__ __forceinline__ void async16(const u16* g, u16* l) {
    __builtin_amdgcn_global_load_lds(
        (const __attribute__((address_space(1))) unsigned int*)(g),
        (__attribute__((address_space(3))) unsigned int*)(l), 16, 0, 0);
}

// ---------------- convert x (fp32 -> bf16), 8 elems/thread ----------------
__global__ void cvt_x(const float* __restrict__ x, u16* __restrict__ o) {
    int i = blockIdx.x * 256 + threadIdx.x;
    const fx4* xv = (const fx4*)x;
    fx4 a = xv[i * 2], b = xv[i * 2 + 1];
    u16x8 r;
    r[0] = f2bf(a[0]); r[1] = f2bf(a[1]); r[2] = f2bf(a[2]); r[3] = f2bf(a[3]);
    r[4] = f2bf(b[0]); r[5] = f2bf(b[1]); r[6] = f2bf(b[2]); r[7] = f2bf(b[3]);
    ((u16x8*)o)[i] = r;
}

// ---------------- transpose + convert weights: (2048 x 2048) fp32 -> bf16 N x K ----------------
__global__ void transpose_cvt(const float* W0, const float* W1, const float* W2, const float* W3,
                              u16* O0, u16* O1, u16* O2, u16* O3) {
    const float* W; u16* O;
    switch (blockIdx.z) {
        case 0: W = W0; O = O0; break;
        case 1: W = W1; O = O1; break;
        case 2: W = W2; O = O2; break;
        default: W = W3; O = O3; break;
    }
    __shared__ u16 tile[32][33];
    int bx = blockIdx.x * 32, by = blockIdx.y * 32;
    int tx = threadIdx.x, ty = threadIdx.y;
#pragma unroll
    for (int i = 0; i < 32; i += 8)
        tile[ty + i][tx] = f2bf(W[(long)(by + ty + i) * 2048 + bx + tx]);
    __syncthreads();
#pragma unroll
    for (int i = 0; i < 32; i += 8)
        O[(long)(bx + ty + i) * 2048 + by + tx] = tile[tx][ty + i];
}

// ---------------- m97-style GEMM: C(MxN) = A(MxK) * BT(NxK)^T, bf16 in ----------------
// grid: (N/128 fast, M/128) so consecutive blocks share one A-tile and B stays L2/LLC-hot.
template <typename OutT>
__global__ __launch_bounds__(256) void gemm_bt(const u16* __restrict__ A, const u16* __restrict__ BT,
                                               OutT* __restrict__ C, int M_, int N_, int K_) {
    __shared__ __align__(16) u16 As[4096];  // 128 x 32
    __shared__ __align__(16) u16 Bs[4096];  // 128 x 32
    const int t = threadIdx.x, w = t >> 6, l = t & 63, lr = l & 15, quad = l >> 4;
    const int bn = blockIdx.x, bm = blockIdx.y;  // bn fast: A-tile reuse across 16 blocks
    const u16* gA[2]; const u16* gB[2]; u16* lA[2]; u16* lB[2];
#pragma unroll
    for (int r = 0; r < 2; r++) {
        int c = r * 256 + t;
        gA[r] = A + (long)(bm * 128 + (c >> 2)) * K_ + (c & 3) * 8;
        gB[r] = BT + (long)(bn * 128 + (c >> 2)) * K_ + (c & 3) * 8;
        lA[r] = &As[(r * 256 + w * 64) * 8];
        lB[r] = &Bs[(r * 256 + w * 64) * 8];
    }
    f32x4 acc[4][4] = {};
    const int wr = (w >> 1) * 64, wc = (w & 1) * 64;
    for (int k0 = 0; k0 < K_; k0 += 32) {
        async16(gA[0] + k0, lA[0]); async16(gA[1] + k0, lA[1]);
        async16(gB[0] + k0, lB[0]); async16(gB[1] + k0, lB[1]);
        __syncthreads();
        bf16x8 af[4], bfr[4];
#pragma unroll
        for (int i = 0; i < 4; i++) af[i] = *(const bf16x8*)&As[(wr + i * 16 + lr) * 32 + quad * 8];
#pragma unroll
        for (int j = 0; j < 4; j++) bfr[j] = *(const bf16x8*)&Bs[(wc + j * 16 + lr) * 32 + quad * 8];
#pragma unroll
        for (int i = 0; i < 4; i++)
#pragma unroll
            for (int j = 0; j < 4; j++) acc[i][j] = MFMA16(af[i], bfr[j], acc[i][j]);
        __syncthreads();
    }
#pragma unroll
    for (int i = 0; i < 4; i++) {
        int row0 = bm * 128 + wr + i * 16 + quad * 4;
#pragma unroll
        for (int j = 0; j < 4; j++) {
            int col = bn * 128 + wc + j * 16 + lr;
#pragma unroll
            for (int rg = 0; rg < 4; rg++) {
                long idx = (long)(row0 + rg) * N_ + col;
                if constexpr (sizeof(OutT) == 2) ((u16*)C)[idx] = f2bf(acc[i][j][rg]);
                else ((float*)C)[idx] = acc[i][j][rg];
            }
        }
    }
}

// ---------------- sparse K/V projection, split-K=4 over D, fp32 partials ----------------
// which==0: ksp[bh][kk][d]  = x[b,tok_kk,:] . WkT[h*128+d,:]
// which==1: vspT[bh][d][kk] = WvT[h*128+d,:] . x[b,tok_kk,:]   (operand roles swapped -> transposed out)
#define KV_SPLIT 4
#define KV_CHUNK (Dz / KV_SPLIT)
__global__ __launch_bounds__(256) void kv_sparse(const u16* __restrict__ xbf, const u16* __restrict__ WkT,
                                                 const u16* __restrict__ WvT, const int* __restrict__ anchor,
                                                 float* __restrict__ part) {
    const int bh = blockIdx.x, which = blockIdx.y, split = blockIdx.z;
    const int b = bh >> 4, h = bh & 15;
    __shared__ int toks[128];
    __shared__ __align__(16) u16 As[4096];
    __shared__ __align__(16) u16 Bs[4096];
    const int t = threadIdx.x, w = t >> 6, l = t & 63, lr = l & 15, quad = l >> 4;
    if (t < 128) {
        int j = t >> 4;
        int tile = (j == 7) ? (Sz / TILEz - 1) : anchor[bh * NTz + j];
        toks[t] = tile * TILEz + (t & 15);
    }
    __syncthreads();
    const u16* gA[2]; const u16* gB[2]; u16* lA[2]; u16* lB[2];
#pragma unroll
    for (int r = 0; r < 2; r++) {
        int c = r * 256 + t;
        int row = c >> 2, col8 = (c & 3) * 8;
        const u16* xrow = xbf + ((long)b * Sz + toks[row]) * Dz + col8;
        const u16* wrowK = WkT + (long)(h * HDz + row) * Dz + col8;
        const u16* wrowV = WvT + (long)(h * HDz + row) * Dz + col8;
        gA[r] = (which == 0) ? xrow : wrowV;
        gB[r] = (which == 0) ? wrowK : xrow;
        lA[r] = &As[(r * 256 + w * 64) * 8];
        lB[r] = &Bs[(r * 256 + w * 64) * 8];
    }
    f32x4 acc[4][4] = {};
    const int wr = (w >> 1) * 64, wc = (w & 1) * 64;
    const int ks0 = split * KV_CHUNK;
    for (int k0 = ks0; k0 < ks0 + KV_CHUNK; k0 += 32) {
        async16(gA[0] + k0, lA[0]); async16(gA[1] + k0, lA[1]);
        async16(gB[0] + k0, lB[0]); async16(gB[1] + k0, lB[1]);
        __syncthreads();
        bf16x8 af[4], bfr[4];
#pragma unroll
        for (int i = 0; i < 4; i++) af[i] = *(const bf16x8*)&As[(wr + i * 16 + lr) * 32 + quad * 8];
#pragma unroll
        for (int j = 0; j < 4; j++) bfr[j] = *(const bf16x8*)&Bs[(wc + j * 16 + lr) * 32 + quad * 8];
#pragma unroll
        for (int i = 0; i < 4; i++)
#pragma unroll
            for (int j = 0; j < 4; j++) acc[i][j] = MFMA16(af[i], bfr[j], acc[i][j]);
        __syncthreads();
    }
    // partial layout: [split][which][bh][128*128]
    float* out = part + (((long)split * 2 + which) * 64 + bh) * 16384;
#pragma unroll
    for (int i = 0; i < 4; i++) {
        int row0 = wr + i * 16 + quad * 4;
#pragma unroll
        for (int j = 0; j < 4; j++) {
            int col = wc + j * 16 + lr;
#pragma unroll
            for (int rg = 0; rg < 4; rg++) out[(row0 + rg) * 128 + col] = acc[i][j][rg];
        }
    }
}

// reduce KV_SPLIT fp32 partials -> bf16 kv buffer (ksp || vspT contiguous)
__global__ void kv_reduce(const float* __restrict__ part, u16* __restrict__ kv) {
    long i = ((long)blockIdx.x * 256 + threadIdx.x) * 4;  // 2*64*16384 / (2048*256*4) = 1
    const long stride = 2L * 64 * 16384;
    fx4 s = *(const fx4*)(part + i);
#pragma unroll
    for (int sp = 1; sp < KV_SPLIT; sp++) {
        fx4 p = *(const fx4*)(part + sp * stride + i);
        s[0] += p[0]; s[1] += p[1]; s[2] += p[2]; s[3] += p[3];
    }
    u16x4 r;
    r[0] = f2bf(s[0]); r[1] = f2bf(s[1]); r[2] = f2bf(s[2]); r[3] = f2bf(s[3]);
    *(u16x4*)(kv + i) = r;
}

// ---------------- attention: per (128-query tile, h, b) ----------------
__global__ __launch_bounds__(256) void attn_kernel(u16* QAO,  // Q in (B*S,2048), out written in place (disjoint tiles)
                                                   const u16* __restrict__ ksp, const u16* __restrict__ vspT,
                                                   const int* __restrict__ anchor) {
    const int st = blockIdx.x, h = blockIdx.y, b = blockIdx.z;
    const int bh = b * Hz + h, s0 = st * 128;
    __shared__ __align__(16) u16 Ps[128 * 136];  // pad 128->136 to dodge bank conflicts
    __shared__ int toks[128];
    const int t = threadIdx.x, w = t >> 6, l = t & 63, lr = l & 15, quad = l >> 4;
    if (t < 128) {
        int j = t >> 4;
        int tile = (j == 7) ? (Sz / TILEz - 1) : anchor[bh * NTz + j];
        toks[t] = tile * TILEz + (t & 15);
    }
    __syncthreads();
    const u16* Qb = QAO + (long)(b * Sz + s0 + w * 32) * 2048 + h * HDz;
    const u16* Kb = ksp + (long)bh * HDz * 128;   // [key][d]
    const u16* Vb = vspT + (long)bh * HDz * 128;  // [d][key]
    // --- S = Q K^T : wave w owns query rows w*32..w*32+31, all 128 keys ---
    f32x4 acc[2][8] = {};
#pragma unroll
    for (int ks = 0; ks < 4; ks++) {
        bf16x8 a0 = *(const bf16x8*)(Qb + (long)lr * 2048 + ks * 32 + quad * 8);
        bf16x8 a1 = *(const bf16x8*)(Qb + (long)(16 + lr) * 2048 + ks * 32 + quad * 8);
#pragma unroll
        for (int j = 0; j < 8; j++) {
            bf16x8 bj = *(const bf16x8*)(Kb + (j * 16 + lr) * 128 + ks * 32 + quad * 8);
            acc[0][j] = MFMA16(a0, bj, acc[0][j]);
            acc[1][j] = MFMA16(a1, bj, acc[1][j]);
        }
    }
    // --- mask + softmax, fully in-register (rows live in 16-lane quad groups) ---
    int tokj[8];
#pragma unroll
    for (int j = 0; j < 8; j++) tokj[j] = toks[j * 16 + lr];
    const float scale = 0.08838834764831845f;  // 1/sqrt(128)
#pragma unroll
    for (int i = 0; i < 2; i++) {
#pragma unroll
        for (int rg = 0; rg < 4; rg++) {
            int qpos = s0 + w * 32 + i * 16 + quad * 4 + rg;
            float v[8];
#pragma unroll
            for (int j = 0; j < 8; j++)
                v[j] = (tokj[j] > qpos) ? -1e10f : acc[i][j][rg] * scale;
            float mx = v[0];
#pragma unroll
            for (int j = 1; j < 8; j++) mx = fmaxf(mx, v[j]);
            mx = fmaxf(mx, __shfl_xor(mx, 1, 64));
            mx = fmaxf(mx, __shfl_xor(mx, 2, 64));
            mx = fmaxf(mx, __shfl_xor(mx, 4, 64));
            mx = fmaxf(mx, __shfl_xor(mx, 8, 64));
            float s = 0.f;
#pragma unroll
            for (int j = 0; j < 8; j++) { v[j] = exp2f((v[j] - mx) * 1.4426950408889634f); s += v[j]; }
            s += __shfl_xor(s, 1, 64);
            s += __shfl_xor(s, 2, 64);
            s += __shfl_xor(s, 4, 64);
            s += __shfl_xor(s, 8, 64);
            float rs = 1.0f / s;
            int prow = w * 32 + i * 16 + quad * 4 + rg;
#pragma unroll
            for (int j = 0; j < 8; j++) Ps[prow * 136 + j * 16 + lr] = f2bf(v[j] * rs);
        }
    }
    __syncthreads();
    // --- O^T = V^T P^T : wave w owns d-rows w*32..w*32+31, all 128 queries ---
    f32x4 oacc[2][8] = {};
#pragma unroll
    for (int ks = 0; ks < 4; ks++) {
        bf16x8 a0 = *(const bf16x8*)(Vb + (w * 32 + lr) * 128 + ks * 32 + quad * 8);
        bf16x8 a1 = *(const bf16x8*)(Vb + (w * 32 + 16 + lr) * 128 + ks * 32 + quad * 8);
#pragma unroll
        for (int j = 0; j < 8; j++) {
            bf16x8 bj = *(const bf16x8*)&Ps[(j * 16 + lr) * 136 + ks * 32 + quad * 8];
            oacc[0][j] = MFMA16(a0, bj, oacc[0][j]);
            oacc[1][j] = MFMA16(a1, bj, oacc[1][j]);
        }
    }
#pragma unroll
    for (int i = 0; i < 2; i++) {
#pragma unroll
        for (int j = 0; j < 8; j++) {
            u16x4 pk;
#pragma unroll
            for (int rg = 0; rg < 4; rg++) pk[rg] = f2bf(oacc[i][j][rg]);
            int d = w * 32 + i * 16 + quad * 4;
            int q = j * 16 + lr;
            *(u16x4*)(QAO + (long)(b * Sz + s0 + q) * 2048 + h * HDz + d) = pk;
        }
    }
}

extern "C" void kernel_launch(void* const* d_in, const int* in_sizes, int n_in,
                              void* d_out, int out_size, void* d_ws, size_t ws_size,
                              hipStream_t stream) {
    const float* x = (const float*)d_in[0];
    const int* anchor = (const int*)d_in[1];
    const float* Wq = (const float*)d_in[2];
    const float* Wk = (const float*)d_in[3];
    const float* Wv = (const float*)d_in[4];
    const float* Wo = (const float*)d_in[5];

    char* ws = (char*)d_ws;
    const size_t XB = 67108864;   // x bf16: 16384*2048*2
    const size_t WB = 8388608;    // one weight bf16: 2048*2048*2
    u16* xbf = (u16*)(ws);
    u16* WqT = (u16*)(ws + XB);
    u16* WkT = (u16*)(ws + XB + WB);
    u16* WvT = (u16*)(ws + XB + 2 * WB);
    u16* WoT = (u16*)(ws + XB + 3 * WB);
    u16* Qb  = (u16*)(ws + XB + 4 * WB);            // Q, then attn out (aliased, disjoint tiles)
    float* kvpart = (float*)(ws + XB + 4 * WB);     // overlays Qb: used BEFORE Q-gemm writes it (33.5 MB < 67 MB)
    u16* ksp = (u16*)(ws + 2 * XB + 4 * WB);        // (B*H,128,128)
    u16* vspT= (u16*)(ws + 2 * XB + 4 * WB + 2097152);

    cvt_x<<<16384, 256, 0, stream>>>(x, xbf);
    transpose_cvt<<<dim3(64, 64, 4), dim3(32, 8), 0, stream>>>(Wq, Wk, Wv, Wo, WqT, WkT, WvT, WoT);
    // K/V sparse projection first (partials overlay the Q buffer region, reduced before Q-gemm runs)
    kv_sparse<<<dim3(64, 2, KV_SPLIT), 256, 0, stream>>>(xbf, WkT, WvT, anchor, kvpart);
    kv_reduce<<<2048, 256, 0, stream>>>(kvpart, ksp);
    gemm_bt<u16><<<dim3(16, 128), 256, 0, stream>>>(xbf, WqT, Qb, 16384, 2048, 2048);
    attn_kernel<<<dim3(32, 16, 4), 256, 0, stream>>>(Qb, ksp, vspT, anchor);
    gemm_bt<float><<<dim3(16, 128), 256, 0, stream>>>(Qb, WoT, (float*)d_out, 16384, 2048, 2048);
}